// Round 8
// baseline (531.765 us; speedup 1.0000x reference)
//
#include <hip/hip_runtime.h>
#include <hip/hip_fp16.h>

typedef unsigned int uint32;
typedef _Float16 f16;
typedef f16 f16x4 __attribute__((ext_vector_type(4)));
typedef f16 f16x8 __attribute__((ext_vector_type(8)));
typedef float f32x4 __attribute__((ext_vector_type(4)));

union U8 { f16x8 v; uint4 u4; uint2 u2[2]; f16 h[8]; };

__device__ __forceinline__ float h2f(__half v) { return __half2float(v); }
__device__ __forceinline__ __half f2h(float v) { return __float2half(v); }

// ---------------------------------------------------------------------------
// K0_w1: conv1_w -> W1T[48][192] f16, n-major, zero-padded.
// ---------------------------------------------------------------------------
__global__ __launch_bounds__(256) void k0_w1(const float* __restrict__ W1,
                                             f16* __restrict__ W1T) {
  int i = blockIdx.x * 256 + threadIdx.x;
  if (i < 9216) {
    int n = i / 192, k = i % 192;
    W1T[i] = (n < 36 && k < 180) ? (f16)W1[k * 36 + n] : (f16)0;
  }
}

// ---------------------------------------------------------------------------
// K1 (MFMA, no LDS, no barriers): t1 = leaky_relu(x @ conv1_w + b1), f16 out.
// ---------------------------------------------------------------------------
__global__ __launch_bounds__(256) void k1_conv1(const float* __restrict__ X,
                                                const f16* __restrict__ W1T,
                                                const float* __restrict__ B1,
                                                __half* __restrict__ T1) {
  int t = threadIdx.x;
  int p0 = blockIdx.x * 128;
  int lane = t & 63, wave = t >> 6;
  int lm = lane & 15, lq = lane >> 4;

  f16x8 ax[6][2];
#pragma unroll
  for (int mt = 0; mt < 2; ++mt) {
    int row = p0 + wave * 32 + mt * 16 + lm;
    const float* xr = X + (size_t)row * 180;
#pragma unroll
    for (int ch = 0; ch < 6; ++ch) {
      int k0 = ch * 32 + lq * 8;
      U8 v; v.u4 = (uint4){0u, 0u, 0u, 0u};
      if (k0 + 8 <= 180) {
        float4 a = *(const float4*)&xr[k0];
        float4 b = *(const float4*)&xr[k0 + 4];
        v.h[0]=(f16)a.x; v.h[1]=(f16)a.y; v.h[2]=(f16)a.z; v.h[3]=(f16)a.w;
        v.h[4]=(f16)b.x; v.h[5]=(f16)b.y; v.h[6]=(f16)b.z; v.h[7]=(f16)b.w;
      } else if (k0 < 180) {  // k0 == 176
        float4 a = *(const float4*)&xr[k0];
        v.h[0]=(f16)a.x; v.h[1]=(f16)a.y; v.h[2]=(f16)a.z; v.h[3]=(f16)a.w;
      }
      ax[ch][mt] = v.v;
    }
  }

  f32x4 acc[2][3];
#pragma unroll
  for (int mt = 0; mt < 2; ++mt)
#pragma unroll
    for (int nt = 0; nt < 3; ++nt) acc[mt][nt] = (f32x4){0.f, 0.f, 0.f, 0.f};

#pragma unroll
  for (int ch = 0; ch < 6; ++ch) {
#pragma unroll
    for (int nt = 0; nt < 3; ++nt) {
      int n = nt * 16 + lm;   // < 48, rows >=36 are zeros
      f16x8 bf = *(const f16x8*)&W1T[n * 192 + ch * 32 + lq * 8];
      acc[0][nt] = __builtin_amdgcn_mfma_f32_16x16x32_f16(
          ax[ch][0], bf, acc[0][nt], 0, 0, 0);
      acc[1][nt] = __builtin_amdgcn_mfma_f32_16x16x32_f16(
          ax[ch][1], bf, acc[1][nt], 0, 0, 0);
    }
  }

  float bb[3];
#pragma unroll
  for (int nt = 0; nt < 3; ++nt) {
    int co = nt * 16 + lm;
    bb[nt] = (co < 36) ? B1[co] : 0.f;
  }
#pragma unroll
  for (int mt = 0; mt < 2; ++mt) {
#pragma unroll
    for (int reg = 0; reg < 4; ++reg) {
      int p = p0 + wave * 32 + mt * 16 + lq * 4 + reg;
      __half* o = T1 + (size_t)p * 36;
#pragma unroll
      for (int nt = 0; nt < 3; ++nt) {
        int co = nt * 16 + lm;
        if (co < 36) {
          float v = acc[mt][nt][reg] + bb[nt];
          o[co] = f2h(v > 0.f ? v : 0.2f * v);
        }
      }
    }
  }
}

// ---------------------------------------------------------------------------
// K0_w2: conv2_w -> W2T[9][48][40] f16, n-major per tap, zero-padded.
// ---------------------------------------------------------------------------
__global__ __launch_bounds__(256) void k0_w2(const float* __restrict__ W2,
                                             f16* __restrict__ W2T) {
  int i = blockIdx.x * 256 + threadIdx.x;
  if (i < 17280) {
    int tap = i / 1920, rem = i % 1920, n = rem / 40, k = rem % 40;
    W2T[i] = (n < 36 && k < 36) ? (f16)W2[(tap * 36 + k) * 36 + n] : (f16)0;
  }
}

// ---------------------------------------------------------------------------
// K2 (MFMA implicit GEMM): t2 = leaky_relu(conv3x3(t1)+b2).
// ---------------------------------------------------------------------------
__global__ __launch_bounds__(256) void k2_conv2(const __half* __restrict__ T1,
                                                const f16* __restrict__ W2T,
                                                const float* __restrict__ B2,
                                                __half* __restrict__ T2) {
  __shared__ __align__(16) f16 ins[3 * 132 * 40];  // [kh][xx][ci40]
  int t = threadIdx.x;
  int p0 = blockIdx.x * 128;
  int b = p0 >> 16, y = (p0 >> 8) & 255, x0 = p0 & 255;

  const uint32* T1u = (const uint32*)T1;   // rows are 18 u32
  uint32* insu = (uint32*)ins;             // [kh][xx][20 u32]
  for (int i = t; i < 7920; i += 256) {    // 3*132*20
    int kh = i / 2640, rem = i % 2640;
    int xx = rem / 20, u = rem % 20;
    int ry = y + kh - 1, gx = x0 + xx - 1;
    uint32 v = 0u;
    if (u < 18 && xx < 130 && (unsigned)ry < 256u && (unsigned)gx < 256u)
      v = T1u[((size_t)((b * 256 + ry) * 256 + gx)) * 18 + u];
    insu[i] = v;                           // i == (kh*132+xx)*20+u
  }
  __syncthreads();

  int lane = t & 63, wave = t >> 6;
  int lm = lane & 15, lq = lane >> 4;
  const f16x8 zero8 = {(f16)0,(f16)0,(f16)0,(f16)0,(f16)0,(f16)0,(f16)0,(f16)0};

  f32x4 acc[2][3];
#pragma unroll
  for (int mt = 0; mt < 2; ++mt)
#pragma unroll
    for (int nt = 0; nt < 3; ++nt) acc[mt][nt] = (f32x4){0.f, 0.f, 0.f, 0.f};

#pragma unroll
  for (int kh = 0; kh < 3; ++kh) {
#pragma unroll
    for (int kw = 0; kw < 3; ++kw) {
      int tap = kh * 3 + kw;
      f16x8 a0[2], a1[2];
#pragma unroll
      for (int mt = 0; mt < 2; ++mt) {
        int xx = wave * 32 + mt * 16 + lm + kw;   // <= 129
        const f16* ar = &ins[(kh * 132 + xx) * 40];
        a0[mt] = *(const f16x8*)&ar[lq * 8];
        a1[mt] = (lq == 0) ? *(const f16x8*)&ar[32] : zero8;
      }
#pragma unroll
      for (int nt = 0; nt < 3; ++nt) {
        const f16* br = &W2T[(tap * 48 + nt * 16 + lm) * 40];
        f16x8 b0 = *(const f16x8*)&br[lq * 8];
        f16x8 b1 = (lq == 0) ? *(const f16x8*)&br[32] : zero8;
#pragma unroll
        for (int mt = 0; mt < 2; ++mt) {
          acc[mt][nt] = __builtin_amdgcn_mfma_f32_16x16x32_f16(
              a0[mt], b0, acc[mt][nt], 0, 0, 0);
          acc[mt][nt] = __builtin_amdgcn_mfma_f32_16x16x32_f16(
              a1[mt], b1, acc[mt][nt], 0, 0, 0);
        }
      }
    }
  }

  float bb[3];
#pragma unroll
  for (int nt = 0; nt < 3; ++nt) {
    int co = nt * 16 + lm;
    bb[nt] = (co < 36) ? B2[co] : 0.f;
  }
#pragma unroll
  for (int mt = 0; mt < 2; ++mt) {
#pragma unroll
    for (int reg = 0; reg < 4; ++reg) {
      int p = p0 + wave * 32 + mt * 16 + lq * 4 + reg;
      __half* o = T2 + (size_t)p * 36;
#pragma unroll
      for (int nt = 0; nt < 3; ++nt) {
        int co = nt * 16 + lm;
        if (co < 36) {
          float v = acc[mt][nt][reg] + bb[nt];
          o[co] = f2h(v > 0.f ? v : 0.2f * v);
        }
      }
    }
  }
}

// ---------------------------------------------------------------------------
// K0_wt: transpose+convert W3/WD to n-major f16 tables with zero padding.
// ---------------------------------------------------------------------------
__global__ __launch_bounds__(256) void k0_wt(const float* __restrict__ SW3,
                                             const float* __restrict__ SWD,
                                             f16* __restrict__ WT3,
                                             f16* __restrict__ WTD) {
  int tid = blockIdx.x * 256 + threadIdx.x;
  int stride = gridDim.x * 256;
  for (int i = tid; i < 192 * 40; i += stride) {
    int n = i / 40, k = i % 40;
    WT3[i] = (n < 180 && k < 36) ? (f16)SW3[k * 180 + n] : (f16)0;
  }
  for (int i = tid; i < 192 * 192; i += stride) {
    int n = i / 192, k = i % 192;
    WTD[i] = (n < 180 && k < 180) ? (f16)SWD[k * 180 + n] : (f16)0;
  }
}

// K0_pw: same for proj_w -> PWT[192][192]. Launched AFTER k3 (lives over T2).
__global__ __launch_bounds__(256) void k0_pw(const float* __restrict__ SPW,
                                             f16* __restrict__ PWT) {
  int tid = blockIdx.x * 256 + threadIdx.x;
  int stride = gridDim.x * 256;
  for (int i = tid; i < 192 * 192; i += stride) {
    int n = i / 192, k = i % 192;
    PWT[i] = (n < 180 && k < 180) ? (f16)SPW[k * 180 + n] : (f16)0;
  }
}

// ---------------------------------------------------------------------------
// K3 (MFMA, no LDS, no barriers): qv = (t2@W3+b3)*(x@WD+bd), x64 f16,
// windowed scatter.
// ---------------------------------------------------------------------------
__global__ __launch_bounds__(256) void k3_qv(const float* __restrict__ X,
                                             const __half* __restrict__ T2,
                                             const f16* __restrict__ WT3,
                                             const f16* __restrict__ WTD,
                                             const float* __restrict__ B3,
                                             const float* __restrict__ BD,
                                             __half* __restrict__ QX) {
  int t = threadIdx.x;
  int p0 = blockIdx.x * 128;
  int lane = t & 63, wave = t >> 6;
  int lm = lane & 15, lq = lane >> 4;

  const f16x8 zero8 = {(f16)0,(f16)0,(f16)0,(f16)0,(f16)0,(f16)0,(f16)0,(f16)0};

  f16x8 ax[6][2];
  f16x8 at0[2];
  f16x8 at1[2];
#pragma unroll
  for (int mt = 0; mt < 2; ++mt) {
    int row = p0 + wave * 32 + mt * 16 + lm;
    const float* xr = X + (size_t)row * 180;
#pragma unroll
    for (int ch = 0; ch < 6; ++ch) {
      int k0 = ch * 32 + lq * 8;
      U8 v; v.u4 = (uint4){0u, 0u, 0u, 0u};
      if (k0 + 8 <= 180) {
        float4 a = *(const float4*)&xr[k0];
        float4 b = *(const float4*)&xr[k0 + 4];
        v.h[0]=(f16)a.x; v.h[1]=(f16)a.y; v.h[2]=(f16)a.z; v.h[3]=(f16)a.w;
        v.h[4]=(f16)b.x; v.h[5]=(f16)b.y; v.h[6]=(f16)b.z; v.h[7]=(f16)b.w;
      } else if (k0 < 180) {  // k0 == 176
        float4 a = *(const float4*)&xr[k0];
        v.h[0]=(f16)a.x; v.h[1]=(f16)a.y; v.h[2]=(f16)a.z; v.h[3]=(f16)a.w;
      }
      ax[ch][mt] = v.v;
    }
    const f16* tr = (const f16*)T2 + (size_t)row * 36;
    U8 tv;
    tv.u2[0] = *(const uint2*)&tr[lq * 8];
    tv.u2[1] = *(const uint2*)&tr[lq * 8 + 4];
    at0[mt] = tv.v;
    U8 t1v; t1v.u4 = (uint4){0u, 0u, 0u, 0u};
    if (lq == 0) t1v.u2[0] = *(const uint2*)&tr[32];
    at1[mt] = t1v.v;
  }

  for (int bn = 0; bn < 4; ++bn) {
    int n0 = bn * 48;
    f32x4 accC[2][3], accD[2][3];
#pragma unroll
    for (int i = 0; i < 2; ++i)
#pragma unroll
      for (int j = 0; j < 3; ++j) {
        accC[i][j] = (f32x4){0.f, 0.f, 0.f, 0.f};
        accD[i][j] = (f32x4){0.f, 0.f, 0.f, 0.f};
      }

#pragma unroll
    for (int nt = 0; nt < 3; ++nt) {
      int n = n0 + nt * 16 + lm;
      f16x8 b0 = *(const f16x8*)&WT3[n * 40 + lq * 8];
      f16x8 b1 = (lq == 0) ? *(const f16x8*)&WT3[n * 40 + 32] : zero8;
#pragma unroll
      for (int mt = 0; mt < 2; ++mt) {
        accC[mt][nt] = __builtin_amdgcn_mfma_f32_16x16x32_f16(
            at0[mt], b0, accC[mt][nt], 0, 0, 0);
        accC[mt][nt] = __builtin_amdgcn_mfma_f32_16x16x32_f16(
            at1[mt], b1, accC[mt][nt], 0, 0, 0);
      }
    }

#pragma unroll
    for (int ch = 0; ch < 6; ++ch) {
#pragma unroll
      for (int nt = 0; nt < 3; ++nt) {
        int n = n0 + nt * 16 + lm;
        f16x8 bf = *(const f16x8*)&WTD[n * 192 + ch * 32 + lq * 8];
        accD[0][nt] = __builtin_amdgcn_mfma_f32_16x16x32_f16(
            ax[ch][0], bf, accD[0][nt], 0, 0, 0);
        accD[1][nt] = __builtin_amdgcn_mfma_f32_16x16x32_f16(
            ax[ch][1], bf, accD[1][nt], 0, 0, 0);
      }
    }

    float cb[3], db[3];
#pragma unroll
    for (int nt = 0; nt < 3; ++nt) {
      int col = n0 + nt * 16 + lm;
      cb[nt] = (col < 180) ? B3[col] : 0.f;
      db[nt] = (col < 180) ? BD[col] : 0.f;
    }
#pragma unroll
    for (int mt = 0; mt < 2; ++mt) {
#pragma unroll
      for (int reg = 0; reg < 4; ++reg) {
        int p = p0 + wave * 32 + mt * 16 + lq * 4 + reg;
        int b = p >> 16, y = (p >> 8) & 255, x = p & 255;
        int wi = (b << 8) | ((y >> 4) << 4) | (x >> 4);
        int l = ((y & 15) << 4) | (x & 15);
        __half* orow = QX + ((size_t)(wi * 256 + l)) * 180;
#pragma unroll
        for (int nt = 0; nt < 3; ++nt) {
          int col = n0 + nt * 16 + lm;
          if (col < 180)
            orow[col] = f2h((accC[mt][nt][reg] + cb[nt]) *
                            (accD[mt][nt][reg] + db[nt]) * 64.f);
        }
      }
    }
  }
}

// ---------------------------------------------------------------------------
// K5a: position-bias MLP over 961 grid points -> PTAB[961][6] f32
// ---------------------------------------------------------------------------
__device__ __forceinline__ void ln_relu11(const float* p, const float* g,
                                          const float* b, float* r) {
  float m = 0.f;
#pragma unroll
  for (int j = 0; j < 11; ++j) m += p[j];
  m *= (1.0f / 11.0f);
  float v = 0.f;
#pragma unroll
  for (int j = 0; j < 11; ++j) { float d = p[j] - m; v += d * d; }
  v *= (1.0f / 11.0f);
  float inv = 1.0f / sqrtf(v + 1e-5f);
#pragma unroll
  for (int j = 0; j < 11; ++j) {
    float xn = (p[j] - m) * inv * g[j] + b[j];
    r[j] = fmaxf(xn, 0.f);
  }
}
__device__ __forceinline__ void mm11(const float* r, const float* W,
                                     const float* b, float* o) {
#pragma unroll
  for (int j2 = 0; j2 < 11; ++j2) {
    float s = b[j2];
#pragma unroll
    for (int j = 0; j < 11; ++j) s += r[j] * W[j * 11 + j2];
    o[j2] = s;
  }
}

__global__ __launch_bounds__(256) void k5a_posmlp(
    const float* PPW, const float* PPB,
    const float* LN1G, const float* LN1B, const float* M1W, const float* M1B,
    const float* LN2G, const float* LN2B, const float* M2W, const float* M2B,
    const float* LN3G, const float* LN3B, const float* M3W, const float* M3B,
    float* __restrict__ PTAB) {
  int t = blockIdx.x * 256 + threadIdx.x;
  if (t >= 961) return;
  float g0 = (float)(t / 31) - 15.0f;
  float g1 = (float)(t % 31) - 15.0f;
  float p[11], r[11];
#pragma unroll
  for (int j = 0; j < 11; ++j)
    p[j] = g0 * PPW[j] + g1 * PPW[11 + j] + PPB[j];
  ln_relu11(p, LN1G, LN1B, r);
  mm11(r, M1W, M1B, p);
  ln_relu11(p, LN2G, LN2B, r);
  mm11(r, M2W, M2B, p);
  ln_relu11(p, LN3G, LN3B, r);
#pragma unroll
  for (int h = 0; h < 6; ++h) {
    float s = M3B[h];
#pragma unroll
    for (int j = 0; j < 11; ++j) s += r[j] * M3W[j * 6 + h];
    PTAB[t * 6 + h] = s;
  }
}

// ---------------------------------------------------------------------------
// K5b: RPB[h][l][m] = mean over 2x2 of PTAB[(dr+15)*31+(dc+15)][h]
// ---------------------------------------------------------------------------
__global__ __launch_bounds__(256) void k5b_rpb(const float* __restrict__ PTAB,
                                               float* __restrict__ RPB) {
  int t = blockIdx.x * 256 + threadIdx.x;  // < 98304
  int m = t & 63;
  int l = (t >> 6) & 255;
  int h = t >> 14;
  int mh = m >> 3, mw = m & 7;
  int qr = l >> 4, qc = l & 15;
  float s = 0.f;
#pragma unroll
  for (int rh = 0; rh < 2; ++rh)
#pragma unroll
    for (int rw = 0; rw < 2; ++rw) {
      int dr = qr - (mh * 2 + rh) + 15;
      int dc = qc - (mw * 2 + rw) + 15;
      s += PTAB[(dr * 31 + dc) * 6 + h];
    }
  RPB[t] = 0.25f * s;
}

// ---------------------------------------------------------------------------
// K7a (MFMA): cc[c][d] = sum_l q[l][c]*v[l][d] / 256 per window, f32 out.
// 90x90x256 GEMM: q,v staged TRANSPOSED into LDS [96][264] f16 (c-major /
// d-major, rows 90..95 zero, stride 264 -> aligned 16B frags, 2-way-free
// read bank pattern). 36 tiles x 8 K-chunks, 9 tiles/wave, 72 MFMA/wave.
// LDS 101 KB -> 1 block/CU.
// ---------------------------------------------------------------------------
__global__ __launch_bounds__(256) void k7a_cc(const __half* __restrict__ QX,
                                              float* __restrict__ CC) {
  __shared__ __align__(16) f16 qT[96 * 264];
  __shared__ __align__(16) f16 vT[96 * 264];
  int wi = blockIdx.x, t = threadIdx.x;
  const uint32* G = (const uint32*)(QX + (size_t)wi * 46080);
  uint32* qTw = (uint32*)qT;
  uint32* vTw = (uint32*)vT;
  // zero pad rows 90..95 (read by mt/nt==5 frags)
  for (int i = t; i < 792; i += 256) {     // 6 rows x 132 u32
    qTw[90 * 132 + i] = 0u;
    vTw[90 * 132 + i] = 0u;
  }
  // stage transposed: coalesced u32 reads, 2x u16 scatter writes
  for (int i = t; i < 23040; i += 256) {   // 256 rows x 90 u32
    int l = i / 90, j = i % 90;
    union { uint32 w; f16 h[2]; } cv;
    cv.w = G[i];
    if (j < 45) {
      qT[(2 * j) * 264 + l] = cv.h[0];
      qT[(2 * j + 1) * 264 + l] = cv.h[1];
    } else {
      int d = 2 * (j - 45);
      vT[d * 264 + l] = cv.h[0];
      vT[(d + 1) * 264 + l] = cv.h[1];
    }
  }
  __syncthreads();
  int lane = t & 63, w = t >> 6;
  int lm = lane & 15, lq = lane >> 4;
  const float s = 1.0f / (256.0f * 4096.0f);
  for (int id = w; id < 36; id += 4) {
    int mt = id / 6, nt = id % 6;
    f32x4 acc = (f32x4){0.f, 0.f, 0.f, 0.f};
#pragma unroll
    for (int kc = 0; kc < 8; ++kc) {
      f16x8 a = *(const f16x8*)&qT[(mt * 16 + lm) * 264 + kc * 32 + lq * 8];
      f16x8 b = *(const f16x8*)&vT[(nt * 16 + lm) * 264 + kc * 32 + lq * 8];
      acc = __builtin_amdgcn_mfma_f32_16x16x32_f16(a, b, acc, 0, 0, 0);
    }
    int d = nt * 16 + lm;                  // C col = d
    if (d < 90) {
#pragma unroll
      for (int reg = 0; reg < 4; ++reg) {
        int c = mt * 16 + lq * 4 + reg;    // C row = c
        if (c < 90)
          CC[((size_t)(wi * 90 + c)) * 90 + d] = acc[reg] * s;
      }
    }
  }
}

// ---------------------------------------------------------------------------
// KA (MFMA): per window, per head h:
//   corr^T(64x256) = vp(64x16) x q^T ; corr' = corr^T/960 + 256*rpb -> f16;
//   x_sp^T(16x256) = vpT(16x64) x corr'. In place over q-channels, x8192 f16.
// ---------------------------------------------------------------------------
__global__ __launch_bounds__(256) void kA_xsp(__half* __restrict__ QX,
                                              const float* __restrict__ RPB,
                                              const float* __restrict__ SLW,
                                              const float* __restrict__ SLB) {
  __shared__ __align__(16) unsigned char SM[80384];
  f16* U   = (f16*)SM;                    // A: v [256][90]; B: qP [256][104]
  f16* vpS = (f16*)(SM + 53248);          // [64][104] m-major (A1 frags)
  f16* vpT = (f16*)(SM + 66560);          // [96][72]  c-major (A2 frags)
  int wi = blockIdx.x, t = threadIdx.x;
  __half* QW = QX + (size_t)wi * 46080;
  const uint32* G = (const uint32*)QW;
  uint32* Uw = (uint32*)U;

  for (int i = t; i < 11520; i += 256) {
    int l = i / 45, k = i % 45;
    Uw[l * 45 + k] = G[l * 90 + 45 + k];
  }
  __syncthreads();
  float w0 = SLW[0], w1 = SLW[1], w2 = SLW[2], w3 = SLW[3];
  float sb = SLB[0];
  for (int e = t; e < 6144; e += 256) {
    int m = e & 63, idx = e >> 6;          // idx = h*16 + c
    int c = idx & 15, h = idx >> 4;
    f16 val = (f16)0;
    if (c < 15) {
      int ch = h * 15 + c;
      int lb = (m >> 3) * 32 + (m & 7) * 2;
      float s = w0 * (float)U[lb * 90 + ch] + w1 * (float)U[(lb + 1) * 90 + ch]
              + w2 * (float)U[(lb + 16) * 90 + ch] + w3 * (float)U[(lb + 17) * 90 + ch];
      val = (f16)(s * 4.f + sb * 256.f);
    }
    vpS[m * 104 + idx] = val;
    vpT[idx * 72 + m] = val;
  }
  __syncthreads();
  for (int j = t; j < 1536; j += 256) {
    int h = j >> 8, l = j & 255;
    U[l * 104 + h * 16 + 15] = (f16)0;
  }
  for (int i = t; i < 11520; i += 256) {
    int l = i / 45, k = i % 45;
    union { uint32 w; f16 h[2]; } cv;
    cv.w = G[l * 90 + k];
    int cg0 = 2 * k, cg1 = 2 * k + 1;
    int h0 = cg0 / 15, c0 = cg0 - h0 * 15;
    int h1 = cg1 / 15, c1 = cg1 - h1 * 15;
    U[l * 104 + h0 * 16 + c0] = cv.h[0];
    U[l * 104 + h1 * 16 + c1] = cv.h[1];
  }
  __syncthreads();

  int lane = t & 63, w = t >> 6;
  int lm = lane & 15, lq = lane >> 4;
  const float invA = 1.0f / 960.0f;        // 256 / (15*16384)
  for (int h = 0; h < 6; ++h) {
    f16x4 a1[4], b1[4];
#pragma unroll
    for (int mt = 0; mt < 4; ++mt)
      a1[mt] = *(const f16x4*)&vpS[(mt * 16 + lm) * 104 + h * 16 + lq * 4];
#pragma unroll
    for (int lt = 0; lt < 4; ++lt)
      b1[lt] = *(const f16x4*)&U[(w * 64 + lt * 16 + lm) * 104 + h * 16 + lq * 4];
    f32x4 acc1[4][4];
#pragma unroll
    for (int mt = 0; mt < 4; ++mt)
#pragma unroll
      for (int lt = 0; lt < 4; ++lt)
        acc1[mt][lt] = __builtin_amdgcn_mfma_f32_16x16x16f16(
            a1[mt], b1[lt], (f32x4){0.f, 0.f, 0.f, 0.f}, 0, 0, 0);
    f16x4 b2[4][4];
#pragma unroll
    for (int lt = 0; lt < 4; ++lt) {
      int l = w * 64 + lt * 16 + lm;
      const float* rp = RPB + ((size_t)(h * 256 + l)) * 64;
#pragma unroll
      for (int mt = 0; mt < 4; ++mt) {
        float4 rv = *(const float4*)&rp[mt * 16 + lq * 4];
        f16x4 bb;
        bb[0] = (f16)(acc1[mt][lt][0] * invA + rv.x * 256.f);
        bb[1] = (f16)(acc1[mt][lt][1] * invA + rv.y * 256.f);
        bb[2] = (f16)(acc1[mt][lt][2] * invA + rv.z * 256.f);
        bb[3] = (f16)(acc1[mt][lt][3] * invA + rv.w * 256.f);
        b2[mt][lt] = bb;
      }
    }
    f16x4 a2[4];
#pragma unroll
    for (int kt = 0; kt < 4; ++kt)
      a2[kt] = *(const f16x4*)&vpT[(h * 16 + lm) * 72 + kt * 16 + lq * 4];
#pragma unroll
    for (int lt = 0; lt < 4; ++lt) {
      f32x4 acc2 = (f32x4){0.f, 0.f, 0.f, 0.f};
#pragma unroll
      for (int kt = 0; kt < 4; ++kt)
        acc2 = __builtin_amdgcn_mfma_f32_16x16x16f16(a2[kt], b2[kt][lt], acc2, 0, 0, 0);
      int l = w * 64 + lt * 16 + lm;
      __half* orow = QW + l * 180 + h * 15;
#pragma unroll
      for (int reg = 0; reg < 4; ++reg) {
        int c = lq * 4 + reg;
        if (c < 15) orow[c] = f2h(acc2[reg] * 0.125f);   // 65536*x_sp / 8
      }
    }
  }
}

// ---------------------------------------------------------------------------
// KB (MFMA): x_ch[l][c] = sum_d cc[c][d]*v[l][d], in place over v-channels
// as 8192*x_ch (f16).
// ---------------------------------------------------------------------------
__global__ __launch_bounds__(256) void kB_xch(__half* __restrict__ QX,
                                              const float* __restrict__ CC) {
  __shared__ __align__(16) f16 vA[256 * 104];
  __shared__ __align__(16) f16 ccB[96 * 104];
  int wi = blockIdx.x, t = threadIdx.x;
  __half* QW = QX + (size_t)wi * 46080;
  const uint32* G = (const uint32*)QW;
  uint32* vAw = (uint32*)vA;
  for (int i = t; i < 12288; i += 256) {   // 256 rows x 48 u32 (cols 0..95)
    int l = i / 48, kk = i % 48;
    vAw[l * 52 + kk] = (kk < 45) ? G[l * 90 + 45 + kk] : 0u;
  }
  const float* ccg = CC + (size_t)wi * 8100;
  uint32* ccw = (uint32*)ccB;
  for (int i = t; i < 4992; i += 256) {    // 96 rows x 52 u32, zero pads
    int c = i / 52, dd = i % 52;
    uint32 out = 0u;
    if (c < 90 && dd < 45) {
      float2 f = *(const float2*)&ccg[c * 90 + dd * 2];
      union { uint32 w; f16 h[2]; } cv;
      cv.h[0] = (f16)(f.x * 65536.f);
      cv.h[1] = (f16)(f.y * 65536.f);
      out = cv.w;
    }
    ccw[c * 52 + dd] = out;
  }
  __syncthreads();
  int lane = t & 63, w = t >> 6;
  int lm = lane & 15, lq = lane >> 4;
  f32x4 acc[4][6];
#pragma unroll
  for (int mt = 0; mt < 4; ++mt)
#pragma unroll
    for (int nt = 0; nt < 6; ++nt) acc[mt][nt] = (f32x4){0.f, 0.f, 0.f, 0.f};
  for (int kc = 0; kc < 3; ++kc) {
    f16x8 af[4], bf[6];
#pragma unroll
    for (int mt = 0; mt < 4; ++mt)
      af[mt] = *(const f16x8*)&vA[(w * 64 + mt * 16 + lm) * 104 + kc * 32 + lq * 8];
#pragma unroll
    for (int nt = 0; nt < 6; ++nt)
      bf[nt] = *(const f16x8*)&ccB[(nt * 16 + lm) * 104 + kc * 32 + lq * 8];
#pragma unroll
    for (int mt = 0; mt < 4; ++mt)
#pragma unroll
      for (int nt = 0; nt < 6; ++nt)
        acc[mt][nt] = __builtin_amdgcn_mfma_f32_16x16x32_f16(
            af[mt], bf[nt], acc[mt][nt], 0, 0, 0);
  }
#pragma unroll
  for (int mt = 0; mt < 4; ++mt) {
#pragma unroll
    for (int reg = 0; reg < 4; ++reg) {
      int l = w * 64 + mt * 16 + lq * 4 + reg;
      __half* orow = QW + l * 180 + 90;
#pragma unroll
      for (int nt = 0; nt < 6; ++nt) {
        int c = nt * 16 + lm;
        if (c < 90) orow[c] = f2h(acc[mt][nt][reg] * 0.001953125f);  // 2^22 -> 2^13
      }
    }
  }
}

// ---------------------------------------------------------------------------
// K8 (MFMA, no LDS, no barriers): out = (XS/8192) @ proj_w + proj_b, f32 out,
// window-reverse scatter.
// ---------------------------------------------------------------------------
__global__ __launch_bounds__(256) void k8_proj(const __half* __restrict__ XS,
                                               const f16* __restrict__ PWT,
                                               const float* __restrict__ PB,
                                               float* __restrict__ OUT) {
  int t = threadIdx.x;
  int w0r = blockIdx.x * 128;
  int lane = t & 63, wave = t >> 6;
  int lm = lane & 15, lq = lane >> 4;

  f16x8 ax[6][2];
#pragma unroll
  for (int mt = 0; mt < 2; ++mt) {
    int row = w0r + wave * 32 + mt * 16 + lm;
    const f16* xr = (const f16*)XS + (size_t)row * 180;
#pragma unroll
    for (int ch = 0; ch < 6; ++ch) {
      int k0 = ch * 32 + lq * 8;
      U8 v; v.u4 = (uint4){0u, 0u, 0u, 0u};
      if (k0 + 8 <= 180) {
        v.u2[0] = *(const uint2*)&xr[k0];
        v.u2[1] = *(const uint2*)&xr[k0 + 4];
      } else if (k0 < 180) {  // k0 == 176
        v.u2[0] = *(const uint2*)&xr[k0];
      }
      ax[ch][mt] = v.v;
    }
  }

  for (int bn = 0; bn < 4; ++bn) {
    int n0 = bn * 48;
    f32x4 acc[2][3];
#pragma unroll
    for (int i = 0; i < 2; ++i)
#pragma unroll
      for (int j = 0; j < 3; ++j) acc[i][j] = (f32x4){0.f, 0.f, 0.f, 0.f};

#pragma unroll
    for (int ch = 0; ch < 6; ++ch) {
#pragma unroll
      for (int nt = 0; nt < 3; ++nt) {
        int n = n0 + nt * 16 + lm;
        f16x8 bf = *(const f16x8*)&PWT[n * 192 + ch * 32 + lq * 8];
        acc[0][nt] = __builtin_amdgcn_mfma_f32_16x16x32_f16(
            ax[ch][0], bf, acc[0][nt], 0, 0, 0);
        acc[1][nt] = __builtin_amdgcn_mfma_f32_16x16x32_f16(
            ax[ch][1], bf, acc[1][nt], 0, 0, 0);
      }
    }

    float pb[3];
#pragma unroll
    for (int nt = 0; nt < 3; ++nt) {
      int col = n0 + nt * 16 + lm;
      pb[nt] = (col < 180) ? PB[col] : 0.f;
    }
    const float inv = 1.0f / 8192.0f;
#pragma unroll
    for (int mt = 0; mt < 2; ++mt) {
#pragma unroll
      for (int reg = 0; reg < 4; ++reg) {
        int w = w0r + wave * 32 + mt * 16 + lq * 4 + reg;
        int wi = w >> 8, l = w & 255;
        int b = wi >> 8, wy = (wi >> 4) & 15, wx = wi & 15;
        int ly = l >> 4, lx = l & 15;
        int p = (b << 16) | (((wy << 4) | ly) << 8) | ((wx << 4) | lx);
        float* orow = OUT + (size_t)p * 180;
#pragma unroll
        for (int nt = 0; nt < 3; ++nt) {
          int col = n0 + nt * 16 + lm;
          if (col < 180) orow[col] = acc[mt][nt][reg] * inv + pb[nt];
        }
      }
    }
  }
}

// ---------------------------------------------------------------------------
// Workspace layout (bytes) — peak requirement 66,060,288 (63.0 MB):
//  W2T f16 [9][48][40]      @ 0            (34,560)  k0_w2, dead after k2
//  W1T f16 [48][192]        @ 34,560       (18,432)  k0_w1, dead after k1;
//                                                    QX overwrites (k3)
//  QX  f16 [512][256][180]  @ 0            (47,185,920)  qv*64 -> XS in place
//  T1  f16 [131072][36]     @ 47,185,920   ( 9,437,184)  dead after k2
//  T2  f16 [131072][36]     @ 56,623,104   ( 9,437,184)  dead after k3
//  PTAB f32 [961*6]         @ 47,185,920   over dead T1
//  RPB  f32 [6][256][64]    @ 47,212,544   over dead T1 (ends 47,605,760)
//  WT3  f16 [192][40]       @ 47,605,760   (15,360)  k0_wt (post-k2)
//  WTD  f16 [192][192]      @ 47,621,120   (73,728)  dead after k3; CC
//                                                    overwrites both (k7a)
//  CC   f32 [512][90][90]   @ 47,605,760   (16,588,800, ends 64,194,560)
//  PWT  f16 [192][192]      @ 64,194,560   (73,728)  k0_pw (post-k3)
// ---------------------------------------------------------------------------
extern "C" void kernel_launch(void* const* d_in, const int* in_sizes, int n_in,
                              void* d_out, int out_size, void* d_ws, size_t ws_size,
                              hipStream_t stream) {
  const float* X    = (const float*)d_in[0];
  const float* W1   = (const float*)d_in[1];
  const float* B1   = (const float*)d_in[2];
  const float* W2   = (const float*)d_in[3];
  const float* B2   = (const float*)d_in[4];
  const float* W3   = (const float*)d_in[5];
  const float* B3c  = (const float*)d_in[6];
  const float* WD   = (const float*)d_in[7];
  const float* BD   = (const float*)d_in[8];
  const float* SLW  = (const float*)d_in[9];
  const float* SLB  = (const float*)d_in[10];
  const float* PPW  = (const float*)d_in[11];
  const float* PPB  = (const float*)d_in[12];
  const float* LN1G = (const float*)d_in[13];
  const float* LN1B = (const float*)d_in[14];
  const float* M1W  = (const float*)d_in[15];
  const float* M1B  = (const float*)d_in[16];
  const float* LN2G = (const float*)d_in[17];
  const float* LN2B = (const float*)d_in[18];
  const float* M2W  = (const float*)d_in[19];
  const float* M2B  = (const float*)d_in[20];
  const float* LN3G = (const float*)d_in[21];
  const float* LN3B = (const float*)d_in[22];
  const float* M3W  = (const float*)d_in[23];
  const float* M3B  = (const float*)d_in[24];
  const float* PW   = (const float*)d_in[25];
  const float* PB   = (const float*)d_in[26];
  float* OUT = (float*)d_out;

  char* ws = (char*)d_ws;
  f16*   W2T  = (f16*)(ws);
  f16*   W1T  = (f16*)(ws + 34560);
  __half* QX  = (__half*)(ws);
  __half* T1  = (__half*)(ws + 47185920);
  __half* T2  = (__half*)(ws + 56623104);
  float* PTAB = (float*)(ws + 47185920);
  float* RPB  = (float*)(ws + 47212544);
  f16*   WT3  = (f16*)(ws + 47605760);
  f16*   WTD  = (f16*)(ws + 47621120);
  float* CC   = (float*)(ws + 47605760);
  f16*   PWT  = (f16*)(ws + 64194560);

  hipLaunchKernelGGL(k0_w2, dim3(68), dim3(256), 0, stream, W2, W2T);
  hipLaunchKernelGGL(k0_w1, dim3(36), dim3(256), 0, stream, W1, W1T);
  hipLaunchKernelGGL(k1_conv1, dim3(1024), dim3(256), 0, stream, X, W1T, B1, T1);
  hipLaunchKernelGGL(k2_conv2, dim3(1024), dim3(256), 0, stream, T1, W2T, B2, T2);
  hipLaunchKernelGGL(k0_wt, dim3(144), dim3(256), 0, stream, W3, WD, WT3, WTD);
  hipLaunchKernelGGL(k3_qv, dim3(1024), dim3(256), 0, stream, X, T2, WT3, WTD, B3c, BD, QX);
  hipLaunchKernelGGL(k0_pw, dim3(144), dim3(256), 0, stream, PW, PWT);
  hipLaunchKernelGGL(k5a_posmlp, dim3(4), dim3(256), 0, stream,
                     PPW, PPB, LN1G, LN1B, M1W, M1B, LN2G, LN2B, M2W, M2B,
                     LN3G, LN3B, M3W, M3B, PTAB);
  hipLaunchKernelGGL(k5b_rpb, dim3(384), dim3(256), 0, stream, PTAB, RPB);
  hipLaunchKernelGGL(k7a_cc, dim3(512), dim3(256), 0, stream, QX, CC);
  hipLaunchKernelGGL(kA_xsp, dim3(512), dim3(256), 0, stream, QX, RPB, SLW, SLB);
  hipLaunchKernelGGL(kB_xch, dim3(512), dim3(256), 0, stream, QX, CC);
  hipLaunchKernelGGL(k8_proj, dim3(1024), dim3(256), 0, stream, QX, PWT, PB, OUT);
}

// Round 9
// 525.588 us; speedup vs baseline: 1.0118x; 1.0118x over previous
//
#include <hip/hip_runtime.h>
#include <hip/hip_fp16.h>

typedef unsigned int uint32;
typedef _Float16 f16;
typedef f16 f16x4 __attribute__((ext_vector_type(4)));
typedef f16 f16x8 __attribute__((ext_vector_type(8)));
typedef float f32x4 __attribute__((ext_vector_type(4)));

union U8 { f16x8 v; uint4 u4; uint2 u2[2]; f16 h[8]; };

__device__ __forceinline__ float h2f(__half v) { return __half2float(v); }
__device__ __forceinline__ __half f2h(float v) { return __float2half(v); }

// ---------------------------------------------------------------------------
// K0_w1: conv1_w -> W1T[48][192] f16, n-major, zero-padded.
// ---------------------------------------------------------------------------
__global__ __launch_bounds__(256) void k0_w1(const float* __restrict__ W1,
                                             f16* __restrict__ W1T) {
  int i = blockIdx.x * 256 + threadIdx.x;
  if (i < 9216) {
    int n = i / 192, k = i % 192;
    W1T[i] = (n < 36 && k < 180) ? (f16)W1[k * 36 + n] : (f16)0;
  }
}

// ---------------------------------------------------------------------------
// K1 (MFMA, no LDS, no barriers): t1 = leaky_relu(x @ conv1_w + b1), f16 out.
// ---------------------------------------------------------------------------
__global__ __launch_bounds__(256) void k1_conv1(const float* __restrict__ X,
                                                const f16* __restrict__ W1T,
                                                const float* __restrict__ B1,
                                                __half* __restrict__ T1) {
  int t = threadIdx.x;
  int p0 = blockIdx.x * 128;
  int lane = t & 63, wave = t >> 6;
  int lm = lane & 15, lq = lane >> 4;

  f16x8 ax[6][2];
#pragma unroll
  for (int mt = 0; mt < 2; ++mt) {
    int row = p0 + wave * 32 + mt * 16 + lm;
    const float* xr = X + (size_t)row * 180;
#pragma unroll
    for (int ch = 0; ch < 6; ++ch) {
      int k0 = ch * 32 + lq * 8;
      U8 v; v.u4 = (uint4){0u, 0u, 0u, 0u};
      if (k0 + 8 <= 180) {
        float4 a = *(const float4*)&xr[k0];
        float4 b = *(const float4*)&xr[k0 + 4];
        v.h[0]=(f16)a.x; v.h[1]=(f16)a.y; v.h[2]=(f16)a.z; v.h[3]=(f16)a.w;
        v.h[4]=(f16)b.x; v.h[5]=(f16)b.y; v.h[6]=(f16)b.z; v.h[7]=(f16)b.w;
      } else if (k0 < 180) {  // k0 == 176
        float4 a = *(const float4*)&xr[k0];
        v.h[0]=(f16)a.x; v.h[1]=(f16)a.y; v.h[2]=(f16)a.z; v.h[3]=(f16)a.w;
      }
      ax[ch][mt] = v.v;
    }
  }

  f32x4 acc[2][3];
#pragma unroll
  for (int mt = 0; mt < 2; ++mt)
#pragma unroll
    for (int nt = 0; nt < 3; ++nt) acc[mt][nt] = (f32x4){0.f, 0.f, 0.f, 0.f};

#pragma unroll
  for (int ch = 0; ch < 6; ++ch) {
#pragma unroll
    for (int nt = 0; nt < 3; ++nt) {
      int n = nt * 16 + lm;   // < 48, rows >=36 are zeros
      f16x8 bf = *(const f16x8*)&W1T[n * 192 + ch * 32 + lq * 8];
      acc[0][nt] = __builtin_amdgcn_mfma_f32_16x16x32_f16(
          ax[ch][0], bf, acc[0][nt], 0, 0, 0);
      acc[1][nt] = __builtin_amdgcn_mfma_f32_16x16x32_f16(
          ax[ch][1], bf, acc[1][nt], 0, 0, 0);
    }
  }

  float bb[3];
#pragma unroll
  for (int nt = 0; nt < 3; ++nt) {
    int co = nt * 16 + lm;
    bb[nt] = (co < 36) ? B1[co] : 0.f;
  }
#pragma unroll
  for (int mt = 0; mt < 2; ++mt) {
#pragma unroll
    for (int reg = 0; reg < 4; ++reg) {
      int p = p0 + wave * 32 + mt * 16 + lq * 4 + reg;
      __half* o = T1 + (size_t)p * 36;
#pragma unroll
      for (int nt = 0; nt < 3; ++nt) {
        int co = nt * 16 + lm;
        if (co < 36) {
          float v = acc[mt][nt][reg] + bb[nt];
          o[co] = f2h(v > 0.f ? v : 0.2f * v);
        }
      }
    }
  }
}

// ---------------------------------------------------------------------------
// K0_w2: conv2_w -> W2T[9][48][40] f16, n-major per tap, zero-padded.
// ---------------------------------------------------------------------------
__global__ __launch_bounds__(256) void k0_w2(const float* __restrict__ W2,
                                             f16* __restrict__ W2T) {
  int i = blockIdx.x * 256 + threadIdx.x;
  if (i < 17280) {
    int tap = i / 1920, rem = i % 1920, n = rem / 40, k = rem % 40;
    W2T[i] = (n < 36 && k < 36) ? (f16)W2[(tap * 36 + k) * 36 + n] : (f16)0;
  }
}

// ---------------------------------------------------------------------------
// K2 (MFMA implicit GEMM): t2 = leaky_relu(conv3x3(t1)+b2).
// ---------------------------------------------------------------------------
__global__ __launch_bounds__(256) void k2_conv2(const __half* __restrict__ T1,
                                                const f16* __restrict__ W2T,
                                                const float* __restrict__ B2,
                                                __half* __restrict__ T2) {
  __shared__ __align__(16) f16 ins[3 * 132 * 40];  // [kh][xx][ci40]
  int t = threadIdx.x;
  int p0 = blockIdx.x * 128;
  int b = p0 >> 16, y = (p0 >> 8) & 255, x0 = p0 & 255;

  const uint32* T1u = (const uint32*)T1;   // rows are 18 u32
  uint32* insu = (uint32*)ins;             // [kh][xx][20 u32]
  for (int i = t; i < 7920; i += 256) {    // 3*132*20
    int kh = i / 2640, rem = i % 2640;
    int xx = rem / 20, u = rem % 20;
    int ry = y + kh - 1, gx = x0 + xx - 1;
    uint32 v = 0u;
    if (u < 18 && xx < 130 && (unsigned)ry < 256u && (unsigned)gx < 256u)
      v = T1u[((size_t)((b * 256 + ry) * 256 + gx)) * 18 + u];
    insu[i] = v;                           // i == (kh*132+xx)*20+u
  }
  __syncthreads();

  int lane = t & 63, wave = t >> 6;
  int lm = lane & 15, lq = lane >> 4;
  const f16x8 zero8 = {(f16)0,(f16)0,(f16)0,(f16)0,(f16)0,(f16)0,(f16)0,(f16)0};

  f32x4 acc[2][3];
#pragma unroll
  for (int mt = 0; mt < 2; ++mt)
#pragma unroll
    for (int nt = 0; nt < 3; ++nt) acc[mt][nt] = (f32x4){0.f, 0.f, 0.f, 0.f};

#pragma unroll
  for (int kh = 0; kh < 3; ++kh) {
#pragma unroll
    for (int kw = 0; kw < 3; ++kw) {
      int tap = kh * 3 + kw;
      f16x8 a0[2], a1[2];
#pragma unroll
      for (int mt = 0; mt < 2; ++mt) {
        int xx = wave * 32 + mt * 16 + lm + kw;   // <= 129
        const f16* ar = &ins[(kh * 132 + xx) * 40];
        a0[mt] = *(const f16x8*)&ar[lq * 8];
        a1[mt] = (lq == 0) ? *(const f16x8*)&ar[32] : zero8;
      }
#pragma unroll
      for (int nt = 0; nt < 3; ++nt) {
        const f16* br = &W2T[(tap * 48 + nt * 16 + lm) * 40];
        f16x8 b0 = *(const f16x8*)&br[lq * 8];
        f16x8 b1 = (lq == 0) ? *(const f16x8*)&br[32] : zero8;
#pragma unroll
        for (int mt = 0; mt < 2; ++mt) {
          acc[mt][nt] = __builtin_amdgcn_mfma_f32_16x16x32_f16(
              a0[mt], b0, acc[mt][nt], 0, 0, 0);
          acc[mt][nt] = __builtin_amdgcn_mfma_f32_16x16x32_f16(
              a1[mt], b1, acc[mt][nt], 0, 0, 0);
        }
      }
    }
  }

  float bb[3];
#pragma unroll
  for (int nt = 0; nt < 3; ++nt) {
    int co = nt * 16 + lm;
    bb[nt] = (co < 36) ? B2[co] : 0.f;
  }
#pragma unroll
  for (int mt = 0; mt < 2; ++mt) {
#pragma unroll
    for (int reg = 0; reg < 4; ++reg) {
      int p = p0 + wave * 32 + mt * 16 + lq * 4 + reg;
      __half* o = T2 + (size_t)p * 36;
#pragma unroll
      for (int nt = 0; nt < 3; ++nt) {
        int co = nt * 16 + lm;
        if (co < 36) {
          float v = acc[mt][nt][reg] + bb[nt];
          o[co] = f2h(v > 0.f ? v : 0.2f * v);
        }
      }
    }
  }
}

// ---------------------------------------------------------------------------
// K0_wt: transpose+convert W3/WD to n-major f16 tables with zero padding.
// ---------------------------------------------------------------------------
__global__ __launch_bounds__(256) void k0_wt(const float* __restrict__ SW3,
                                             const float* __restrict__ SWD,
                                             f16* __restrict__ WT3,
                                             f16* __restrict__ WTD) {
  int tid = blockIdx.x * 256 + threadIdx.x;
  int stride = gridDim.x * 256;
  for (int i = tid; i < 192 * 40; i += stride) {
    int n = i / 40, k = i % 40;
    WT3[i] = (n < 180 && k < 36) ? (f16)SW3[k * 180 + n] : (f16)0;
  }
  for (int i = tid; i < 192 * 192; i += stride) {
    int n = i / 192, k = i % 192;
    WTD[i] = (n < 180 && k < 180) ? (f16)SWD[k * 180 + n] : (f16)0;
  }
}

// K0_pw: same for proj_w -> PWT[192][192]. Launched AFTER k3 (lives over T2).
__global__ __launch_bounds__(256) void k0_pw(const float* __restrict__ SPW,
                                             f16* __restrict__ PWT) {
  int tid = blockIdx.x * 256 + threadIdx.x;
  int stride = gridDim.x * 256;
  for (int i = tid; i < 192 * 192; i += stride) {
    int n = i / 192, k = i % 192;
    PWT[i] = (n < 180 && k < 180) ? (f16)SPW[k * 180 + n] : (f16)0;
  }
}

// ---------------------------------------------------------------------------
// K3 (MFMA): qv = (t2@W3+b3)*(x@WD+bd), x64 f16, windowed scatter.
// A-frags in registers; B-frags from L2 tables. Epilogue repacks each
// wave's 32x48 C-quadrant through WAVE-PRIVATE LDS (no barriers; same-wave
// LDS ops are in-order) then stores coalesced 8B uint2 chunks (row base is
// 8B-aligned; 180 % 4 == 0 so chunks never straddle the valid boundary).
// ---------------------------------------------------------------------------
__global__ __launch_bounds__(256) void k3_qv(const float* __restrict__ X,
                                             const __half* __restrict__ T2,
                                             const f16* __restrict__ WT3,
                                             const f16* __restrict__ WTD,
                                             const float* __restrict__ B3,
                                             const float* __restrict__ BD,
                                             __half* __restrict__ QX) {
  __shared__ __align__(16) f16 eplds[4 * 32 * 56];  // wave-private 32x56
  int t = threadIdx.x;
  int p0 = blockIdx.x * 128;
  int lane = t & 63, wave = t >> 6;
  int lm = lane & 15, lq = lane >> 4;

  const f16x8 zero8 = {(f16)0,(f16)0,(f16)0,(f16)0,(f16)0,(f16)0,(f16)0,(f16)0};

  f16x8 ax[6][2];
  f16x8 at0[2];
  f16x8 at1[2];
#pragma unroll
  for (int mt = 0; mt < 2; ++mt) {
    int row = p0 + wave * 32 + mt * 16 + lm;
    const float* xr = X + (size_t)row * 180;
#pragma unroll
    for (int ch = 0; ch < 6; ++ch) {
      int k0 = ch * 32 + lq * 8;
      U8 v; v.u4 = (uint4){0u, 0u, 0u, 0u};
      if (k0 + 8 <= 180) {
        float4 a = *(const float4*)&xr[k0];
        float4 b = *(const float4*)&xr[k0 + 4];
        v.h[0]=(f16)a.x; v.h[1]=(f16)a.y; v.h[2]=(f16)a.z; v.h[3]=(f16)a.w;
        v.h[4]=(f16)b.x; v.h[5]=(f16)b.y; v.h[6]=(f16)b.z; v.h[7]=(f16)b.w;
      } else if (k0 < 180) {  // k0 == 176
        float4 a = *(const float4*)&xr[k0];
        v.h[0]=(f16)a.x; v.h[1]=(f16)a.y; v.h[2]=(f16)a.z; v.h[3]=(f16)a.w;
      }
      ax[ch][mt] = v.v;
    }
    const f16* tr = (const f16*)T2 + (size_t)row * 36;
    U8 tv;
    tv.u2[0] = *(const uint2*)&tr[lq * 8];
    tv.u2[1] = *(const uint2*)&tr[lq * 8 + 4];
    at0[mt] = tv.v;
    U8 t1v; t1v.u4 = (uint4){0u, 0u, 0u, 0u};
    if (lq == 0) t1v.u2[0] = *(const uint2*)&tr[32];
    at1[mt] = t1v.v;
  }

  f16* myl = eplds + wave * 1792;
  for (int bn = 0; bn < 4; ++bn) {
    int n0 = bn * 48;
    f32x4 accC[2][3], accD[2][3];
#pragma unroll
    for (int i = 0; i < 2; ++i)
#pragma unroll
      for (int j = 0; j < 3; ++j) {
        accC[i][j] = (f32x4){0.f, 0.f, 0.f, 0.f};
        accD[i][j] = (f32x4){0.f, 0.f, 0.f, 0.f};
      }

#pragma unroll
    for (int nt = 0; nt < 3; ++nt) {
      int n = n0 + nt * 16 + lm;
      f16x8 b0 = *(const f16x8*)&WT3[n * 40 + lq * 8];
      f16x8 b1 = (lq == 0) ? *(const f16x8*)&WT3[n * 40 + 32] : zero8;
#pragma unroll
      for (int mt = 0; mt < 2; ++mt) {
        accC[mt][nt] = __builtin_amdgcn_mfma_f32_16x16x32_f16(
            at0[mt], b0, accC[mt][nt], 0, 0, 0);
        accC[mt][nt] = __builtin_amdgcn_mfma_f32_16x16x32_f16(
            at1[mt], b1, accC[mt][nt], 0, 0, 0);
      }
    }

#pragma unroll
    for (int ch = 0; ch < 6; ++ch) {
#pragma unroll
      for (int nt = 0; nt < 3; ++nt) {
        int n = n0 + nt * 16 + lm;
        f16x8 bf = *(const f16x8*)&WTD[n * 192 + ch * 32 + lq * 8];
        accD[0][nt] = __builtin_amdgcn_mfma_f32_16x16x32_f16(
            ax[ch][0], bf, accD[0][nt], 0, 0, 0);
        accD[1][nt] = __builtin_amdgcn_mfma_f32_16x16x32_f16(
            ax[ch][1], bf, accD[1][nt], 0, 0, 0);
      }
    }

    float cb[3], db[3];
#pragma unroll
    for (int nt = 0; nt < 3; ++nt) {
      int col = n0 + nt * 16 + lm;
      cb[nt] = (col < 180) ? B3[col] : 0.f;
      db[nt] = (col < 180) ? BD[col] : 0.f;
    }
    // ---- repack through wave-private LDS ----
#pragma unroll
    for (int mt = 0; mt < 2; ++mt)
#pragma unroll
      for (int reg = 0; reg < 4; ++reg) {
        int r = mt * 16 + lq * 4 + reg;
#pragma unroll
        for (int nt = 0; nt < 3; ++nt)
          myl[r * 56 + nt * 16 + lm] =
              (f16)((accC[mt][nt][reg] + cb[nt]) *
                    (accD[mt][nt][reg] + db[nt]) * 64.f);
      }
    // ---- coalesced 8B stores (4 f16 per chunk) ----
#pragma unroll
    for (int it = 0; it < 6; ++it) {
      int idx = it * 64 + lane;          // 0..383 = 32 rows x 12 chunks
      int r = idx / 12, c4 = idx % 12;
      int col = n0 + c4 * 4;
      if (col < 180) {
        int p = p0 + wave * 32 + r;
        int b = p >> 16, y = (p >> 8) & 255, x = p & 255;
        int wi = (b << 8) | ((y >> 4) << 4) | (x >> 4);
        int l = ((y & 15) << 4) | (x & 15);
        uint2 val = *(const uint2*)&myl[r * 56 + c4 * 4];
        *(uint2*)((f16*)QX + ((size_t)(wi * 256 + l)) * 180 + col) = val;
      }
    }
  }
}

// ---------------------------------------------------------------------------
// K5a: position-bias MLP over 961 grid points -> PTAB[961][6] f32
// ---------------------------------------------------------------------------
__device__ __forceinline__ void ln_relu11(const float* p, const float* g,
                                          const float* b, float* r) {
  float m = 0.f;
#pragma unroll
  for (int j = 0; j < 11; ++j) m += p[j];
  m *= (1.0f / 11.0f);
  float v = 0.f;
#pragma unroll
  for (int j = 0; j < 11; ++j) { float d = p[j] - m; v += d * d; }
  v *= (1.0f / 11.0f);
  float inv = 1.0f / sqrtf(v + 1e-5f);
#pragma unroll
  for (int j = 0; j < 11; ++j) {
    float xn = (p[j] - m) * inv * g[j] + b[j];
    r[j] = fmaxf(xn, 0.f);
  }
}
__device__ __forceinline__ void mm11(const float* r, const float* W,
                                     const float* b, float* o) {
#pragma unroll
  for (int j2 = 0; j2 < 11; ++j2) {
    float s = b[j2];
#pragma unroll
    for (int j = 0; j < 11; ++j) s += r[j] * W[j * 11 + j2];
    o[j2] = s;
  }
}

__global__ __launch_bounds__(256) void k5a_posmlp(
    const float* PPW, const float* PPB,
    const float* LN1G, const float* LN1B, const float* M1W, const float* M1B,
    const float* LN2G, const float* LN2B, const float* M2W, const float* M2B,
    const float* LN3G, const float* LN3B, const float* M3W, const float* M3B,
    float* __restrict__ PTAB) {
  int t = blockIdx.x * 256 + threadIdx.x;
  if (t >= 961) return;
  float g0 = (float)(t / 31) - 15.0f;
  float g1 = (float)(t % 31) - 15.0f;
  float p[11], r[11];
#pragma unroll
  for (int j = 0; j < 11; ++j)
    p[j] = g0 * PPW[j] + g1 * PPW[11 + j] + PPB[j];
  ln_relu11(p, LN1G, LN1B, r);
  mm11(r, M1W, M1B, p);
  ln_relu11(p, LN2G, LN2B, r);
  mm11(r, M2W, M2B, p);
  ln_relu11(p, LN3G, LN3B, r);
#pragma unroll
  for (int h = 0; h < 6; ++h) {
    float s = M3B[h];
#pragma unroll
    for (int j = 0; j < 11; ++j) s += r[j] * M3W[j * 6 + h];
    PTAB[t * 6 + h] = s;
  }
}

// ---------------------------------------------------------------------------
// K5b: RPB[h][l][m] = mean over 2x2 of PTAB[(dr+15)*31+(dc+15)][h]
// ---------------------------------------------------------------------------
__global__ __launch_bounds__(256) void k5b_rpb(const float* __restrict__ PTAB,
                                               float* __restrict__ RPB) {
  int t = blockIdx.x * 256 + threadIdx.x;  // < 98304
  int m = t & 63;
  int l = (t >> 6) & 255;
  int h = t >> 14;
  int mh = m >> 3, mw = m & 7;
  int qr = l >> 4, qc = l & 15;
  float s = 0.f;
#pragma unroll
  for (int rh = 0; rh < 2; ++rh)
#pragma unroll
    for (int rw = 0; rw < 2; ++rw) {
      int dr = qr - (mh * 2 + rh) + 15;
      int dc = qc - (mw * 2 + rw) + 15;
      s += PTAB[(dr * 31 + dc) * 6 + h];
    }
  RPB[t] = 0.25f * s;
}

// ---------------------------------------------------------------------------
// K7a: cc[wi][c][d] = sum_l q[l][c]*v[l][d] / 256, f32 out (true scale).
// (scalar version — round-8 MFMA rewrite regressed: 101KB LDS -> 1 block/CU
// + ~11-way staging bank conflict; reverted per post-mortem.)
// ---------------------------------------------------------------------------
__global__ __launch_bounds__(256) void k7a_cc(const __half* __restrict__ QX,
                                              float* __restrict__ CC) {
  __shared__ __half qs[64 * 90];
  __shared__ __half vs[64 * 90];
  int wi = blockIdx.x, t = threadIdx.x;
  int c0 = (t % 15) * 6, d0 = (t / 15) * 6;
  bool act = t < 225;
  float acc[36];
#pragma unroll
  for (int i = 0; i < 36; ++i) acc[i] = 0.f;
  const uint32* G = (const uint32*)(QX + (size_t)wi * 46080);
  uint32* qsw = (uint32*)qs;
  uint32* vsw = (uint32*)vs;
  for (int pass = 0; pass < 4; ++pass) {
    __syncthreads();
    for (int i = t; i < 2880; i += 256) {
      int l = i / 45, k = i % 45;
      int gw = (pass * 64 + l) * 90;
      qsw[l * 45 + k] = G[gw + k];
      vsw[l * 45 + k] = G[gw + 45 + k];
    }
    __syncthreads();
    if (act) {
      for (int l = 0; l < 64; ++l) {
        const __half2* qh = (const __half2*)&qs[l * 90 + c0];
        const __half2* vh = (const __half2*)&vs[l * 90 + d0];
        float a[6], b[6];
#pragma unroll
        for (int k = 0; k < 3; ++k) {
          __half2 x = qh[k];
          a[2 * k] = __low2float(x); a[2 * k + 1] = __high2float(x);
          __half2 y = vh[k];
          b[2 * k] = __low2float(y); b[2 * k + 1] = __high2float(y);
        }
#pragma unroll
        for (int i = 0; i < 6; ++i)
#pragma unroll
          for (int j = 0; j < 6; ++j) acc[i * 6 + j] += a[i] * b[j];
      }
    }
  }
  if (act) {
    const float s = 1.0f / (256.0f * 4096.0f);
#pragma unroll
    for (int i = 0; i < 6; ++i)
#pragma unroll
      for (int j = 0; j < 6; ++j)
        CC[((size_t)(wi * 90 + c0 + i)) * 90 + d0 + j] = acc[i * 6 + j] * s;
  }
}

// ---------------------------------------------------------------------------
// KA (MFMA): per window, per head h:
//   corr^T(64x256) = vp(64x16) x q^T ; corr' = corr^T/960 + 256*rpb -> f16;
//   x_sp^T(16x256) = vpT(16x64) x corr'. In place over q-channels, x8192 f16.
// ---------------------------------------------------------------------------
__global__ __launch_bounds__(256) void kA_xsp(__half* __restrict__ QX,
                                              const float* __restrict__ RPB,
                                              const float* __restrict__ SLW,
                                              const float* __restrict__ SLB) {
  __shared__ __align__(16) unsigned char SM[80384];
  f16* U   = (f16*)SM;                    // A: v [256][90]; B: qP [256][104]
  f16* vpS = (f16*)(SM + 53248);          // [64][104] m-major (A1 frags)
  f16* vpT = (f16*)(SM + 66560);          // [96][72]  c-major (A2 frags)
  int wi = blockIdx.x, t = threadIdx.x;
  __half* QW = QX + (size_t)wi * 46080;
  const uint32* G = (const uint32*)QW;
  uint32* Uw = (uint32*)U;

  for (int i = t; i < 11520; i += 256) {
    int l = i / 45, k = i % 45;
    Uw[l * 45 + k] = G[l * 90 + 45 + k];
  }
  __syncthreads();
  float w0 = SLW[0], w1 = SLW[1], w2 = SLW[2], w3 = SLW[3];
  float sb = SLB[0];
  for (int e = t; e < 6144; e += 256) {
    int m = e & 63, idx = e >> 6;          // idx = h*16 + c
    int c = idx & 15, h = idx >> 4;
    f16 val = (f16)0;
    if (c < 15) {
      int ch = h * 15 + c;
      int lb = (m >> 3) * 32 + (m & 7) * 2;
      float s = w0 * (float)U[lb * 90 + ch] + w1 * (float)U[(lb + 1) * 90 + ch]
              + w2 * (float)U[(lb + 16) * 90 + ch] + w3 * (float)U[(lb + 17) * 90 + ch];
      val = (f16)(s * 4.f + sb * 256.f);
    }
    vpS[m * 104 + idx] = val;
    vpT[idx * 72 + m] = val;
  }
  __syncthreads();
  for (int j = t; j < 1536; j += 256) {
    int h = j >> 8, l = j & 255;
    U[l * 104 + h * 16 + 15] = (f16)0;
  }
  for (int i = t; i < 11520; i += 256) {
    int l = i / 45, k = i % 45;
    union { uint32 w; f16 h[2]; } cv;
    cv.w = G[l * 90 + k];
    int cg0 = 2 * k, cg1 = 2 * k + 1;
    int h0 = cg0 / 15, c0 = cg0 - h0 * 15;
    int h1 = cg1 / 15, c1 = cg1 - h1 * 15;
    U[l * 104 + h0 * 16 + c0] = cv.h[0];
    U[l * 104 + h1 * 16 + c1] = cv.h[1];
  }
  __syncthreads();

  int lane = t & 63, w = t >> 6;
  int lm = lane & 15, lq = lane >> 4;
  const float invA = 1.0f / 960.0f;        // 256 / (15*16384)
  for (int h = 0; h < 6; ++h) {
    f16x4 a1[4], b1[4];
#pragma unroll
    for (int mt = 0; mt < 4; ++mt)
      a1[mt] = *(const f16x4*)&vpS[(mt * 16 + lm) * 104 + h * 16 + lq * 4];
#pragma unroll
    for (int lt = 0; lt < 4; ++lt)
      b1[lt] = *(const f16x4*)&U[(w * 64 + lt * 16 + lm) * 104 + h * 16 + lq * 4];
    f32x4 acc1[4][4];
#pragma unroll
    for (int mt = 0; mt < 4; ++mt)
#pragma unroll
      for (int lt = 0; lt < 4; ++lt)
        acc1[mt][lt] = __builtin_amdgcn_mfma_f32_16x16x16f16(
            a1[mt], b1[lt], (f32x4){0.f, 0.f, 0.f, 0.f}, 0, 0, 0);
    f16x4 b2[4][4];
#pragma unroll
    for (int lt = 0; lt < 4; ++lt) {
      int l = w * 64 + lt * 16 + lm;
      const float* rp = RPB + ((size_t)(h * 256 + l)) * 64;
#pragma unroll
      for (int mt = 0; mt < 4; ++mt) {
        float4 rv = *(const float4*)&rp[mt * 16 + lq * 4];
        f16x4 bb;
        bb[0] = (f16)(acc1[mt][lt][0] * invA + rv.x * 256.f);
        bb[1] = (f16)(acc1[mt][lt][1] * invA + rv.y * 256.f);
        bb[2] = (f16)(acc1[mt][lt][2] * invA + rv.z * 256.f);
        bb[3] = (f16)(acc1[mt][lt][3] * invA + rv.w * 256.f);
        b2[mt][lt] = bb;
      }
    }
    f16x4 a2[4];
#pragma unroll
    for (int kt = 0; kt < 4; ++kt)
      a2[kt] = *(const f16x4*)&vpT[(h * 16 + lm) * 72 + kt * 16 + lq * 4];
#pragma unroll
    for (int lt = 0; lt < 4; ++lt) {
      f32x4 acc2 = (f32x4){0.f, 0.f, 0.f, 0.f};
#pragma unroll
      for (int kt = 0; kt < 4; ++kt)
        acc2 = __builtin_amdgcn_mfma_f32_16x16x16f16(a2[kt], b2[kt][lt], acc2, 0, 0, 0);
      int l = w * 64 + lt * 16 + lm;
      __half* orow = QW + l * 180 + h * 15;
#pragma unroll
      for (int reg = 0; reg < 4; ++reg) {
        int c = lq * 4 + reg;
        if (c < 15) orow[c] = f2h(acc2[reg] * 0.125f);   // 65536*x_sp / 8
      }
    }
  }
}

// ---------------------------------------------------------------------------
// KB (MFMA): x_ch[l][c] = sum_d cc[c][d]*v[l][d], in place over v-channels
// as 8192*x_ch (f16).
// ---------------------------------------------------------------------------
__global__ __launch_bounds__(256) void kB_xch(__half* __restrict__ QX,
                                              const float* __restrict__ CC) {
  __shared__ __align__(16) f16 vA[256 * 104];
  __shared__ __align__(16) f16 ccB[96 * 104];
  int wi = blockIdx.x, t = threadIdx.x;
  __half* QW = QX + (size_t)wi * 46080;
  const uint32* G = (const uint32*)QW;
  uint32* vAw = (uint32*)vA;
  for (int i = t; i < 12288; i += 256) {   // 256 rows x 48 u32 (cols 0..95)
    int l = i / 48, kk = i % 48;
    vAw[l * 52 + kk] = (kk < 45) ? G[l * 90 + 45 + kk] : 0u;
  }
  const float* ccg = CC + (size_t)wi * 8100;
  uint32* ccw = (uint32*)ccB;
  for (int i = t; i < 4992; i += 256) {    // 96 rows x 52 u32, zero pads
    int c = i / 52, dd = i % 52;
    uint32 out = 0u;
    if (c < 90 && dd < 45) {
      float2 f = *(const float2*)&ccg[c * 90 + dd * 2];
      union { uint32 w; f16 h[2]; } cv;
      cv.h[0] = (f16)(f.x * 65536.f);
      cv.h[1] = (f16)(f.y * 65536.f);
      out = cv.w;
    }
    ccw[c * 52 + dd] = out;
  }
  __syncthreads();
  int lane = t & 63, w = t >> 6;
  int lm = lane & 15, lq = lane >> 4;
  f32x4 acc[4][6];
#pragma unroll
  for (int mt = 0; mt < 4; ++mt)
#pragma unroll
    for (int nt = 0; nt < 6; ++nt) acc[mt][nt] = (f32x4){0.f, 0.f, 0.f, 0.f};
  for (int kc = 0; kc < 3; ++kc) {
    f16x8 af[4], bf[6];
#pragma unroll
    for (int mt = 0; mt < 4; ++mt)
      af[mt] = *(const f16x8*)&vA[(w * 64 + mt * 16 + lm) * 104 + kc * 32 + lq * 8];
#pragma unroll
    for (int nt = 0; nt < 6; ++nt)
      bf[nt] = *(const f16x8*)&ccB[(nt * 16 + lm) * 104 + kc * 32 + lq * 8];
#pragma unroll
    for (int mt = 0; mt < 4; ++mt)
#pragma unroll
      for (int nt = 0; nt < 6; ++nt)
        acc[mt][nt] = __builtin_amdgcn_mfma_f32_16x16x32_f16(
            af[mt], bf[nt], acc[mt][nt], 0, 0, 0);
  }
#pragma unroll
  for (int mt = 0; mt < 4; ++mt) {
#pragma unroll
    for (int reg = 0; reg < 4; ++reg) {
      int l = w * 64 + mt * 16 + lq * 4 + reg;
      __half* orow = QW + l * 180 + 90;
#pragma unroll
      for (int nt = 0; nt < 6; ++nt) {
        int c = nt * 16 + lm;
        if (c < 90) orow[c] = f2h(acc[mt][nt][reg] * 0.001953125f);  // 2^22 -> 2^13
      }
    }
  }
}

// ---------------------------------------------------------------------------
// K8 (MFMA, no LDS, no barriers): out = (XS/8192) @ proj_w + proj_b, f32 out,
// window-reverse scatter.
// ---------------------------------------------------------------------------
__global__ __launch_bounds__(256) void k8_proj(const __half* __restrict__ XS,
                                               const f16* __restrict__ PWT,
                                               const float* __restrict__ PB,
                                               float* __restrict__ OUT) {
  int t = threadIdx.x;
  int w0r = blockIdx.x * 128;
  int lane = t & 63, wave = t >> 6;
  int lm = lane & 15, lq = lane >> 4;

  f16x8 ax[6][2];
#pragma unroll
  for (int mt = 0; mt < 2; ++mt) {
    int row = w0r + wave * 32 + mt * 16 + lm;
    const f16* xr = (const f16*)XS + (size_t)row * 180;
#pragma unroll
    for (int ch = 0; ch < 6; ++ch) {
      int k0 = ch * 32 + lq * 8;
      U8 v; v.u4 = (uint4){0u, 0u, 0u, 0u};
      if (k0 + 8 <= 180) {
        v.u2[0] = *(const uint2*)&xr[k0];
        v.u2[1] = *(const uint2*)&xr[k0 + 4];
      } else if (k0 < 180) {  // k0 == 176
        v.u2[0] = *(const uint2*)&xr[k0];
      }
      ax[ch][mt] = v.v;
    }
  }

  for (int bn = 0; bn < 4; ++bn) {
    int n0 = bn * 48;
    f32x4 acc[2][3];
#pragma unroll
    for (int i = 0; i < 2; ++i)
#pragma unroll
      for (int j = 0; j < 3; ++j) acc[i][j] = (f32x4){0.f, 0.f, 0.f, 0.f};

#pragma unroll
    for (int ch = 0; ch < 6; ++ch) {
#pragma unroll
      for (int nt = 0; nt < 3; ++nt) {
        int n = n0 + nt * 16 + lm;
        f16x8 bf = *(const f16x8*)&PWT[n * 192 + ch * 32 + lq * 8];
        acc[0][nt] = __builtin_amdgcn_mfma_f32_16x16x32_f16(
            ax[ch][0], bf, acc[0][nt], 0, 0, 0);
        acc[1][nt] = __builtin_amdgcn_mfma_f32_16x16x32_f16(
            ax[ch][1], bf, acc[1][nt], 0, 0, 0);
      }
    }

    float pb[3];
#pragma unroll
    for (int nt = 0; nt < 3; ++nt) {
      int col = n0 + nt * 16 + lm;
      pb[nt] = (col < 180) ? PB[col] : 0.f;
    }
    const float inv = 1.0f / 8192.0f;
#pragma unroll
    for (int mt = 0; mt < 2; ++mt) {
#pragma unroll
      for (int reg = 0; reg < 4; ++reg) {
        int w = w0r + wave * 32 + mt * 16 + lq * 4 + reg;
        int wi = w >> 8, l = w & 255;
        int b = wi >> 8, wy = (wi >> 4) & 15, wx = wi & 15;
        int ly = l >> 4, lx = l & 15;
        int p = (b << 16) | (((wy << 4) | ly) << 8) | ((wx << 4) | lx);
        float* orow = OUT + (size_t)p * 180;
#pragma unroll
        for (int nt = 0; nt < 3; ++nt) {
          int col = n0 + nt * 16 + lm;
          if (col < 180) orow[col] = acc[mt][nt][reg] * inv + pb[nt];
        }
      }
    }
  }
}

// ---------------------------------------------------------------------------
// Workspace layout: unchanged from round 7 (see prior comments).
// ---------------------------------------------------------------------------
extern "C" void kernel_launch(void* const* d_in, const int* in_sizes, int n_in,
                              void* d_out, int out_size, void* d_ws, size_t ws_size,
                              hipStream_t stream) {
  const float* X    = (const float*)d_in[0];
  const float* W1   = (const float*)d_in[1];
  const float* B1   = (const float*)d_in[2];
  const float* W2   = (const float*)d_in[3];
  const float* B2   = (const float*)d_in[4];
  const float* W3   = (const float*)d_in[5];
  const float* B3c  = (const float*)d_in[6];
  const float* WD   = (const float*)d_in[7];
  const float* BD   = (const float*)d_in[8];
  const float* SLW  = (const float*)d_in[9];
  const float* SLB  = (const float*)d_in[10];
  const float* PPW  = (const float*)d_in[11];
  const float* PPB  = (const float*)d_in[12];
  const float* LN1G = (const float*)d_in[13];
  const float* LN1B = (const float*)d_in[14];
  const float* M1W  = (const float*)d_in[15];
  const float* M1B  = (const float*)d_in[16];
  const float* LN2G = (const float*)d_in[17];
  const float* LN2B = (const float*)d_in[18];
  const float* M2W  = (const float*)d_in[19];
  const float* M2B  = (const float*)d_in[20];
  const float* LN3G = (const float*)d_in[21];
  const float* LN3B = (const float*)d_in[22];
  const float* M3W  = (const float*)d_in[23];
  const float* M3B  = (const float*)d_in[24];
  const float* PW   = (const float*)d_in[25];
  const float* PB   = (const float*)d_in[26];
  float* OUT = (float*)d_out;

  char* ws = (char*)d_ws;
  f16*   W2T  = (f16*)(ws);
  f16*   W1T  = (f16*)(ws + 34560);
  __half* QX  = (__half*)(ws);
  __half* T1  = (__half*)(ws + 47185920);
  __half* T2  = (__half*)(ws + 56623104);
  float* PTAB = (float*)(ws + 47185920);
  float* RPB  = (float*)(ws + 47212544);
  f16*   WT3  = (f16*)(ws + 47605760);
  f16*   WTD  = (f16*)(ws + 47621120);
  float* CC   = (float*)(ws + 47605760);
  f16*   PWT  = (f16*)(ws + 64194560);

  hipLaunchKernelGGL(k0_w2, dim3(68), dim3(256), 0, stream, W2, W2T);
  hipLaunchKernelGGL(k0_w1, dim3(36), dim3(256), 0, stream, W1, W1T);
  hipLaunchKernelGGL(k1_conv1, dim3(1024), dim3(256), 0, stream, X, W1T, B1, T1);
  hipLaunchKernelGGL(k2_conv2, dim3(1024), dim3(256), 0, stream, T1, W2T, B2, T2);
  hipLaunchKernelGGL(k0_wt, dim3(144), dim3(256), 0, stream, W3, WD, WT3, WTD);
  hipLaunchKernelGGL(k3_qv, dim3(1024), dim3(256), 0, stream, X, T2, WT3, WTD, B3c, BD, QX);
  hipLaunchKernelGGL(k0_pw, dim3(144), dim3(256), 0, stream, PW, PWT);
  hipLaunchKernelGGL(k5a_posmlp, dim3(4), dim3(256), 0, stream,
                     PPW, PPB, LN1G, LN1B, M1W, M1B, LN2G, LN2B, M2W, M2B,
                     LN3G, LN3B, M3W, M3B, PTAB);
  hipLaunchKernelGGL(k5b_rpb, dim3(384), dim3(256), 0, stream, PTAB, RPB);
  hipLaunchKernelGGL(k7a_cc, dim3(512), dim3(256), 0, stream, QX, CC);
  hipLaunchKernelGGL(kA_xsp, dim3(512), dim3(256), 0, stream, QX, RPB, SLW, SLB);
  hipLaunchKernelGGL(kB_xch, dim3(512), dim3(256), 0, stream, QX, CC);
  hipLaunchKernelGGL(k8_proj, dim3(1024), dim3(256), 0, stream, QX, PWT, PB, OUT);
}